// Round 8
// baseline (99.559 us; speedup 1.0000x reference)
//
#include <hip/hip_runtime.h>
#include <math.h>

#define Tdim 1024
#define Hh   64

#if __has_builtin(__builtin_amdgcn_exp2f)
#define EXP2(x) __builtin_amdgcn_exp2f(x)
#else
#define EXP2(x) exp2f(x)
#endif

// (1/(sqrt(2)*0.8)) * log2(e) — folded into Q so attention uses exp2 directly
__device__ __constant__ float kQScale = 0.8838834764831844f * 1.4426950408889634f;

// ---------------------------------------------------------------------------
// Kernel 1: fused QKV projection (R5 design, known-good — untouched).
// grid = (128 row-groups of 16, 3), block = 256.
// ---------------------------------------------------------------------------
__global__ __launch_bounds__(256) void qkv_proj(
    const float* __restrict__ x, const float* __restrict__ Wq,
    const float* __restrict__ Wk, const float* __restrict__ Wv,
    float* __restrict__ Q, float* __restrict__ KV)
{
    __shared__ float xs[16][128];     // 8 KB
    __shared__ float Wch[128][36];    // 18 KB, 32-k chunk of W, pad->36

    const int tid  = threadIdx.x;
    const int row0 = blockIdx.x * 16;
    const int w    = blockIdx.y;      // 0=Q 1=K 2=V

    {
        const float4* xg = reinterpret_cast<const float4*>(x + (size_t)row0 * 128);
        reinterpret_cast<float4*>(&xs[0][0])[tid]       = xg[tid];
        reinterpret_cast<float4*>(&xs[0][0])[tid + 256] = xg[tid + 256];
    }

    const float* W = (w == 0) ? Wq : (w == 1) ? Wk : Wv;

    const int j0 = tid & 31;          // cols j0 + {0,32,64,96}
    const int r0 = (tid >> 5) << 1;   // rows r0, r0+1

    float acc[2][4];
#pragma unroll
    for (int r = 0; r < 2; ++r)
#pragma unroll
        for (int c = 0; c < 4; ++c) acc[r][c] = 0.f;

    for (int ch = 0; ch < 4; ++ch) {
        __syncthreads();
#pragma unroll
        for (int s = 0; s < 4; ++s) {
            const int idx  = tid + s * 256;   // 0..1023
            const int rowW = idx >> 3;
            const int c4   = idx & 7;
            *reinterpret_cast<float4*>(&Wch[rowW][c4 * 4]) =
                reinterpret_cast<const float4*>(W + (size_t)rowW * 128 + ch * 32)[c4];
        }
        __syncthreads();

#pragma unroll
        for (int c = 0; c < 8; ++c) {
            const float4 w0 = *reinterpret_cast<const float4*>(&Wch[j0      ][c * 4]);
            const float4 w1 = *reinterpret_cast<const float4*>(&Wch[j0 + 32 ][c * 4]);
            const float4 w2 = *reinterpret_cast<const float4*>(&Wch[j0 + 64 ][c * 4]);
            const float4 w3 = *reinterpret_cast<const float4*>(&Wch[j0 + 96 ][c * 4]);
#pragma unroll
            for (int r = 0; r < 2; ++r) {
                const float4 xv = *reinterpret_cast<const float4*>(&xs[r0 + r][ch * 32 + c * 4]);
                acc[r][0] = fmaf(xv.x, w0.x, fmaf(xv.y, w0.y, fmaf(xv.z, w0.z, fmaf(xv.w, w0.w, acc[r][0]))));
                acc[r][1] = fmaf(xv.x, w1.x, fmaf(xv.y, w1.y, fmaf(xv.z, w1.z, fmaf(xv.w, w1.w, acc[r][1]))));
                acc[r][2] = fmaf(xv.x, w2.x, fmaf(xv.y, w2.y, fmaf(xv.z, w2.z, fmaf(xv.w, w2.w, acc[r][2]))));
                acc[r][3] = fmaf(xv.x, w3.x, fmaf(xv.y, w3.y, fmaf(xv.z, w3.z, fmaf(xv.w, w3.w, acc[r][3]))));
            }
        }
    }

#pragma unroll
    for (int r = 0; r < 2; ++r) {
        const int row = row0 + r0 + r;
        const int bb  = row >> 10;
        const int t   = row & 1023;
#pragma unroll
        for (int jj = 0; jj < 4; ++jj) {
            const int j = j0 + jj * 32;
            const float v = acc[r][jj];
            if (w == 0) {
                Q[(size_t)row * 128 + j] = v * kQScale;
            } else {
                const int h  = j >> 1, dh = j & 1;
                const int bh = bb * Hh + h;
                KV[((size_t)bh * Tdim + t) * 4 + ((w == 1) ? dh : 2 + dh)] = v;
            }
        }
    }
}

// ---------------------------------------------------------------------------
// Kernel 2: causal attention, key-split flash-style. No-max softmax in exp2
// domain -> partial (l, a0, a1) over any key subset are exactly additive.
// Block (c, s, bh): query chunks (c, 15-c) of 64 each; key half s over
// INTERLEAVED 8-key groups ((k>>3)&1 == s) -> balanced prefixes.
// Thread: 2 low + 2 high queries (lq+hq = 1022 const), 8 key sub-lanes.
// grid = (16, 128) = 2048 blocks (8/CU, 32 waves/CU), LDS 8 KB.
// ---------------------------------------------------------------------------
__global__ __launch_bounds__(256) void attn_split(
    const float* __restrict__ Q, const float4* __restrict__ KV,
    float4* __restrict__ P)
{
    __shared__ float4 KVs[512];   // 8 KB, compacted half: key 16m+8s+j -> i=8m+j
    const int tid = threadIdx.x;
    const int c   = blockIdx.x & 7;        // chunk pair
    const int s   = blockIdx.x >> 3;       // key half
    const int bh  = blockIdx.y;
    const int lowb  = c * 64;
    const int highb = (15 - c) * 64;
    const int nhalf = (highb + 64) >> 1;

    const float4* KVg = KV + (size_t)bh * Tdim;
    for (int i = tid; i < nhalf; i += 256) {
        const int gk = ((i >> 3) << 4) + s * 8 + (i & 7);
        KVs[i] = KVg[gk];
    }
    __syncthreads();

    const int sub = tid & 7;
    const int g   = tid >> 3;              // 0..31
    const int lq  = lowb + 2 * g;
    const int hq  = highb + 62 - 2 * g;    // lq + hq = 1022 (balance)
    const int b   = bh >> 6, h = bh & 63;

    const float* Qb = Q + (size_t)b * (Tdim * 128) + h * 2;
    float2 q[4];
    q[0] = *reinterpret_cast<const float2*>(Qb + (size_t)(lq    ) * 128);
    q[1] = *reinterpret_cast<const float2*>(Qb + (size_t)(lq + 1) * 128);
    q[2] = *reinterpret_cast<const float2*>(Qb + (size_t)(hq    ) * 128);
    q[3] = *reinterpret_cast<const float2*>(Qb + (size_t)(hq + 1) * 128);

    float l[4]  = {0.f, 0.f, 0.f, 0.f};
    float a0[4] = {0.f, 0.f, 0.f, 0.f};
    float a1[4] = {0.f, 0.f, 0.f, 0.f};

    auto upd = [&](int i, const float4 kv) {
        const float p = EXP2(fmaf(q[i].x, kv.x, q[i].y * kv.y));
        l[i] += p;
        a0[i] = fmaf(p, kv.z, a0[i]);
        a1[i] = fmaf(p, kv.w, a1[i]);
    };

    // phase 1: keys < lq in this half with key%8 == sub (k = 8s+sub mod 16)
    {
        int i = sub;
        for (int k = s * 8 + sub; k < lq; k += 16, i += 8) {
            const float4 kv = KVs[i];
            upd(0, kv); upd(1, kv); upd(2, kv); upd(3, kv);
        }
    }
    // low diagonal: keys lq, lq+1 (low queries only)
    if (sub <= 1) {
        const int key = lq + sub;
        if (((key >> 3) & 1) == s) {
            const float4 kv = KVs[((key >> 4) << 3) | (key & 7)];
            if (sub == 0) upd(0, kv);
            upd(1, kv);
        }
    }
    // phase 2: keys in [lq, hq) in this half — high queries only
    {
        const int d = (s * 8 + sub - lq) & 15;
        int k = lq + d;
        int i = ((k >> 4) << 3) | sub;
        for (; k < hq; k += 16, i += 8) {
            const float4 kv = KVs[i];
            upd(2, kv); upd(3, kv);
        }
    }
    // high diagonal: keys hq, hq+1
    if (sub <= 1) {
        const int key = hq + sub;
        if (((key >> 3) & 1) == s) {
            const float4 kv = KVs[((key >> 4) << 3) | (key & 7)];
            if (sub == 0) upd(2, kv);
            upd(3, kv);
        }
    }

    // reduce across 8 sub-lanes
#pragma unroll
    for (int i = 0; i < 4; ++i) {
        l[i]  += __shfl_xor(l[i], 1);  l[i]  += __shfl_xor(l[i], 2);  l[i]  += __shfl_xor(l[i], 4);
        a0[i] += __shfl_xor(a0[i], 1); a0[i] += __shfl_xor(a0[i], 2); a0[i] += __shfl_xor(a0[i], 4);
        a1[i] += __shfl_xor(a1[i], 1); a1[i] += __shfl_xor(a1[i], 2); a1[i] += __shfl_xor(a1[i], 4);
    }

    if (sub == 0) {
        float4* Pb = P + ((size_t)(s * 128 + bh) << 10);
        Pb[lq]     = make_float4(l[0], a0[0], a1[0], 0.f);
        Pb[lq + 1] = make_float4(l[1], a0[1], a1[1], 0.f);
        Pb[hq]     = make_float4(l[2], a0[2], a1[2], 0.f);
        Pb[hq + 1] = make_float4(l[3], a0[3], a1[3], 0.f);
    }
}

// ---------------------------------------------------------------------------
// Kernel 2b: combine the two key-half partials and normalize -> O (B,T,D).
// Write-coalesced (lane = head). grid = 512, block = 256.
// ---------------------------------------------------------------------------
__global__ __launch_bounds__(256) void combine(
    const float4* __restrict__ P, float* __restrict__ O)
{
    const int gid = blockIdx.x * 256 + threadIdx.x;   // 0..131071
    const int h = gid & 63;
    const int t = (gid >> 6) & 1023;
    const int b = gid >> 16;
    const int bh = b * Hh + h;
    const float4 pa = P[((size_t)bh << 10) + t];
    const float4 pb = P[((size_t)(128 + bh) << 10) + t];
    const float rl = 1.0f / (pa.x + pb.x);
    *reinterpret_cast<float2*>(O + (size_t)(b * Tdim + t) * 128 + h * 2) =
        make_float2((pa.y + pb.y) * rl, (pa.z + pb.z) * rl);
}

// ---------------------------------------------------------------------------
// Kernel 3: output projection out = O @ Wo.T, col-halved for full-chip use.
// Block (rowg, H): 16 rows x 64 cols. grid = 256, block = 256.
// ---------------------------------------------------------------------------
__global__ __launch_bounds__(256) void out_proj(
    const float* __restrict__ Oin, const float* __restrict__ Wo,
    float* __restrict__ out)
{
    __shared__ float xs[16][128];    // 8 KB
    __shared__ float Wch[64][36];    // 9 KB

    const int tid  = threadIdx.x;
    const int row0 = (blockIdx.x >> 1) * 16;
    const int H    = blockIdx.x & 1;       // col half

    {
        const float4* xg = reinterpret_cast<const float4*>(Oin + (size_t)row0 * 128);
        reinterpret_cast<float4*>(&xs[0][0])[tid]       = xg[tid];
        reinterpret_cast<float4*>(&xs[0][0])[tid + 256] = xg[tid + 256];
    }

    const int j0 = tid & 31;
    const int r0 = (tid >> 5) << 1;

    float acc[2][2] = {{0.f, 0.f}, {0.f, 0.f}};

    for (int ch = 0; ch < 4; ++ch) {
        __syncthreads();
#pragma unroll
        for (int s2 = 0; s2 < 2; ++s2) {
            const int idx  = tid + s2 * 256;   // 0..511
            const int rowW = idx >> 3;
            const int c4   = idx & 7;
            *reinterpret_cast<float4*>(&Wch[rowW][c4 * 4]) =
                reinterpret_cast<const float4*>(
                    Wo + (size_t)(H * 64 + rowW) * 128 + ch * 32)[c4];
        }
        __syncthreads();

#pragma unroll
        for (int cc = 0; cc < 8; ++cc) {
            const float4 w0 = *reinterpret_cast<const float4*>(&Wch[j0     ][cc * 4]);
            const float4 w1 = *reinterpret_cast<const float4*>(&Wch[j0 + 32][cc * 4]);
#pragma unroll
            for (int r = 0; r < 2; ++r) {
                const float4 xv = *reinterpret_cast<const float4*>(&xs[r0 + r][ch * 32 + cc * 4]);
                acc[r][0] = fmaf(xv.x, w0.x, fmaf(xv.y, w0.y, fmaf(xv.z, w0.z, fmaf(xv.w, w0.w, acc[r][0]))));
                acc[r][1] = fmaf(xv.x, w1.x, fmaf(xv.y, w1.y, fmaf(xv.z, w1.z, fmaf(xv.w, w1.w, acc[r][1]))));
            }
        }
    }

#pragma unroll
    for (int r = 0; r < 2; ++r) {
        const int row = row0 + r0 + r;
        out[(size_t)row * 128 + H * 64 + j0]      = acc[r][0];
        out[(size_t)row * 128 + H * 64 + j0 + 32] = acc[r][1];
    }
}

extern "C" void kernel_launch(void* const* d_in, const int* in_sizes, int n_in,
                              void* d_out, int out_size, void* d_ws, size_t ws_size,
                              hipStream_t stream) {
    const float* x  = (const float*)d_in[0];
    const float* Wq = (const float*)d_in[1];
    const float* Wk = (const float*)d_in[2];
    const float* Wv = (const float*)d_in[3];
    const float* Wo = (const float*)d_in[4];
    float* out = (float*)d_out;

    // ws layout (floats): Q 1MB | KV 2MB | P 4MB | O 1MB
    float* ws = (float*)d_ws;
    float* Q  = ws;                    // 262144
    float* KV = ws + 262144;           // 524288
    float* P  = ws + 786432;           // 1048576 (2 halves x 128 bh x 1024 q x float4)
    float* O  = ws + 1835008;          // 262144

    qkv_proj<<<dim3(128, 3), 256, 0, stream>>>(x, Wq, Wk, Wv, Q, KV);
    attn_split<<<dim3(16, 128), 256, 0, stream>>>(Q, (const float4*)KV, (float4*)P);
    combine<<<512, 256, 0, stream>>>((const float4*)P, O);
    out_proj<<<256, 256, 0, stream>>>(O, Wo, out);
}